// Round 14
// baseline (276.853 us; speedup 1.0000x reference)
//
#include <hip/hip_runtime.h>
#include <math.h>

namespace {

constexpr int B = 4;
constexpr int C = 512;
constexpr int NH = 32;          // heads
constexpr int CPH = 16;         // channels per head
constexpr int N = 32 * 32 * 32; // 32768 spatial
constexpr int SCH = 4;          // chunks (1024 n) per kA block, pipelined
constexpr int NJB = 8;          // kA blocks per head (32 chunks / 4)
constexpr int NREC = NJB * 4;   // wave-records per head = 32
constexpr long YSIZE = (long)B * C * N;  // 67,108,864

typedef float f4v __attribute__((ext_vector_type(4)));

__device__ inline float wrs(float v) {
#pragma unroll
  for (int o = 32; o > 0; o >>= 1) v += __shfl_xor(v, o);
  return v;
}

// DPP add, compile-time control + row mask (disabled rows: old=0 added).
template <int CTRL, int RM = 0xF>
__device__ __forceinline__ float dppAdd(float v) {
  const int r = __builtin_amdgcn_update_dpp(
      0, __float_as_int(v), CTRL, RM, 0xF, true);
  return v + __int_as_float(r);
}
// Full 64-lane sum on the VALU pipe only; total valid in row 3 (lanes 48-63).
__device__ __forceinline__ float waveSumRow3(float v) {
  v = dppAdd<0xB1>(v);          // + lane^1
  v = dppAdd<0x4E>(v);          // + lane^2
  v = dppAdd<0x124>(v);         // row_ror:4
  v = dppAdd<0x128>(v);         // row_ror:8 -> 16-lane row sum
  v = dppAdd<0x142, 0xA>(v);    // row_bcast15: rows 1,3 += rows 0,2
  v = dppAdd<0x143, 0xC>(v);    // row_bcast31: rows 2,3 += lower half
  return v;
}

// ---------------------------------------------------------------------------
// kA: single pass over x. grid (8, NH, B) = 1024 blocks (one full generation
// at 4 blocks/CU), 256 threads, __launch_bounds__(256,4) (R13's (256,5)
// spilled the tile -> reverted). Block = 4 pipelined chunks of 1024 n.
// ROTATING-REGISTER PIPELINE: in the d-loop, right after xv[c]'s last read,
// the load of chunk s+1 channel c is issued into xv[c]. Loads trickle out
// through the d-loop, so the long VALU reduction phase always has the next
// chunk's 16 loads in flight -> steady memory issue instead of
// burst-then-idle phase oscillation. Accumulators are post-reduction
// (o0..o3, 4 regs): valid because no max-shift -> plain sums across chunks.
// (No max-shift: logits ~unit variance; fp32 exp safe to 88. Biases & -mu*w
// cancel in softmax; sum_n attn = 1 folds mean subtraction into k4.)
// Record: one 256 B interleaved [p][4] record per wave: float4 at p*4 =
// {dk[p], dq[p], cs[p], s-slot(p==0:sK, p==1:sQ)}.
__global__ __launch_bounds__(256, 4) void kA(const float* __restrict__ x,
                                             const float* __restrict__ kw,
                                             const float* __restrict__ qw,
                                             float* __restrict__ prec) {
  const int b = blockIdx.z, h = blockIdx.y, j = blockIdx.x;
  const int t = threadIdx.x, lane = t & 63, wid = t >> 6;
  const int p = lane & 15;
  const float* xb = x + ((long)(b * C + h * CPH)) * N + (long)j * (SCH * 1024) + t * 4;

  float4 xv[CPH];
  // prologue: chunk 0 tile
#pragma unroll
  for (int c = 0; c < CPH; ++c) xv[c] = *(const float4*)(xb + (long)c * N);

  float o0 = 0.f, o1 = 0.f, o2 = 0.f, o3 = 0.f;

#pragma unroll
  for (int s = 0; s < SCH; ++s) {
    // logits from the resident tile
    float4 lk = make_float4(0.f, 0.f, 0.f, 0.f);
    float4 lq = make_float4(0.f, 0.f, 0.f, 0.f);
#pragma unroll
    for (int c = 0; c < CPH; ++c) {
      const float wkc = kw[h * CPH + c], wqc = qw[h * CPH + c];
      lk.x += xv[c].x * wkc; lk.y += xv[c].y * wkc;
      lk.z += xv[c].z * wkc; lk.w += xv[c].w * wkc;
      lq.x += xv[c].x * wqc; lq.y += xv[c].y * wqc;
      lq.z += xv[c].z * wqc; lq.w += xv[c].w * wqc;
    }
    const float4 ek = make_float4(__expf(lk.x), __expf(lk.y),
                                  __expf(lk.z), __expf(lk.w));
    const float4 eq = make_float4(__expf(lq.x), __expf(lq.y),
                                  __expf(lq.z), __expf(lq.w));
    const float sK = waveSumRow3((ek.x + ek.y) + (ek.z + ek.w));
    const float sQ = waveSumRow3((eq.x + eq.y) + (eq.z + eq.w));
    o3 += (p == 0) ? sK : ((p == 1) ? sQ : 0.f);

    // d-loop with rotating reload: xv[c]'s last read is here, then its
    // register takes the next chunk's channel-c load.
#pragma unroll
    for (int c = 0; c < CPH; ++c) {
      float dk = (xv[c].x * ek.x + xv[c].y * ek.y) + (xv[c].z * ek.z + xv[c].w * ek.w);
      float dq = (xv[c].x * eq.x + xv[c].y * eq.y) + (xv[c].z * eq.z + xv[c].w * eq.w);
      float cs = (xv[c].x + xv[c].y) + (xv[c].z + xv[c].w);
      if (s + 1 < SCH)
        xv[c] = *(const float4*)(xb + (long)(s + 1) * 1024 + (long)c * N);
      dk = waveSumRow3(dk); dq = waveSumRow3(dq); cs = waveSumRow3(cs);
      if (p == c) { o0 += dk; o1 += dq; o2 += cs; }
    }
  }

  const long ridx = (((long)(b * NH + h)) * NJB + j) * 4 + wid;
  if ((lane >> 4) == 3) {  // row 3 holds the valid wave totals
    f4v r; r.x = o0; r.y = o1; r.z = o2; r.w = o3;
    *(f4v*)(prec + ridx * 64 + p * 4) = r;
  }
}

// ---------------------------------------------------------------------------
// k4: combine wave-records + finalize (R9-proven; only NREC 128->32).
// grid(B), 512 threads (thread = channel). Reads records as float4 per
// channel — matches kA's interleaved [p][4] layout.
__global__ __launch_bounds__(512) void k4(const float* __restrict__ prec,
                                          const float* __restrict__ pw1,
                                          const float* __restrict__ pb1,
                                          const float* __restrict__ pw2,
                                          const float* __restrict__ pb2,
                                          float* __restrict__ scale,
                                          float* __restrict__ offset,
                                          float* __restrict__ dpOut) {
  const int b = blockIdx.x;
  const int c = threadIdx.x;           // 0..511
  const int h = c >> 4, i = c & 15;
  const float4* rec4 = (const float4*)prec + ((long)(b * NH + h)) * NREC * 16;

  float dk = 0.f, dq = 0.f, cs = 0.f, sacc = 0.f;
  for (int j = 0; j < NREC; ++j) {
    const float4 r = rec4[j * 16 + i];
    dk += r.x; dq += r.y; cs += r.z; sacc += r.w;  // r.w: sK at i==0, sQ at i==1
  }
  __shared__ float skS[NH], sqS[NH];
  if (i == 0) skS[h] = sacc;
  if (i == 1) sqS[h] = sacc;
  __syncthreads();
  const float sk = skS[h], sq = sqS[h];

  const float mu = cs * (1.f / N);
  const float Kv = dk / sk - mu;
  const float Qv = dq / sq - mu;

  __shared__ float muS[C], h1S[256];
  muS[c] = mu;
  __syncthreads();
  if (c < 256) {
    const int g = c >> 3;
    float a = pb1[c];
#pragma unroll
    for (int k = 0; k < 16; ++k) a += muS[g * 16 + k] * pw1[c * 16 + k];
    h1S[c] = fmaxf(a, 0.f);
  }
  __syncthreads();
  float a = pb2[c];
  const int g2 = c >> 4;
#pragma unroll
  for (int k = 0; k < 8; ++k) a += h1S[g2 * 8 + k] * pw2[c * 8 + k];
  const float P = 1.f / (1.f + __expf(-a));
  scale[b * C + c] = P;
  offset[b * C + c] = (Kv - Qv) * P;

  float pdp = wrs(Kv * Qv);
  __shared__ float pS[8];
  const int lane = c & 63, wid = c >> 6;
  if (lane == 0) pS[wid] = pdp;
  __syncthreads();
  if (c == 0) {
    float tot = 0.f;
    for (int w = 0; w < 8; ++w) tot += pS[w];
    dpOut[b] = tot * (1.f / C);
  }
}

// ---------------------------------------------------------------------------
// k5: y = x * scale[b,c] + offset[b,c] (R12-proven, unchanged).
// grid (N/4096, C, B), block 256. NT loads+stores.
__global__ __launch_bounds__(256) void k5(const float* __restrict__ x,
                                          const float* __restrict__ scale,
                                          const float* __restrict__ offset,
                                          float* __restrict__ y) {
  const int b = blockIdx.z, cc = blockIdx.y;
  const int t = threadIdx.x;
  const long base = ((long)(b * C + cc)) * N + (long)blockIdx.x * 4096;
  const float s = scale[b * C + cc], o = offset[b * C + cc];
#pragma unroll
  for (int k = 0; k < 4; ++k) {
    const long i = base + (long)(k * 256 + t) * 4;
    const f4v v = __builtin_nontemporal_load((const f4v*)(x + i));
    f4v w;
    w.x = v.x * s + o; w.y = v.y * s + o;
    w.z = v.z * s + o; w.w = v.w * s + o;
    __builtin_nontemporal_store(w, (f4v*)(y + i));
  }
}

} // namespace

extern "C" void kernel_launch(void* const* d_in, const int* in_sizes, int n_in,
                              void* d_out, int out_size, void* d_ws, size_t ws_size,
                              hipStream_t stream) {
  const float* x   = (const float*)d_in[0];
  const float* pw1 = (const float*)d_in[1];
  const float* pb1 = (const float*)d_in[2];
  const float* pw2 = (const float*)d_in[3];
  const float* pb2 = (const float*)d_in[4];
  const float* kw  = (const float*)d_in[5];
  // d_in[6]=kb, d_in[8]=qb unused: biases cancel in softmax (shift-invariant);
  // sum_n attn = 1 folds mean-subtraction into the finalize.
  const float* qw  = (const float*)d_in[7];
  float* out = (float*)d_out;
  float* ws  = (float*)d_ws;

  // scale/offset in ws (read by k5 while k5 writes out)
  float* scale  = ws;          // 2048
  float* offset = ws + 2048;   // 2048

  // wave-records: B*NH*NREC*64 = 262,144 floats (1 MB)
  constexpr long PREC = (long)B * NH * NREC * 64;
  float* prec;
  if (ws_size >= (size_t)(4096 + PREC) * sizeof(float)) {
    prec = ws + 4096;
  } else {
    prec = out;  // consumed by k4 before k5 overwrites out
  }

  hipLaunchKernelGGL(kA, dim3(NJB, NH, B), dim3(256), 0, stream,
                     x, kw, qw, prec);
  hipLaunchKernelGGL(k4, dim3(B), dim3(C), 0, stream,
                     prec, pw1, pb1, pw2, pb2, scale, offset, out + YSIZE);
  hipLaunchKernelGGL(k5, dim3(N / 4096, C, B), dim3(256), 0, stream,
                     x, scale, offset, out);
}

// Round 15
// 143.304 us; speedup vs baseline: 1.9319x; 1.9319x over previous
//
#include <hip/hip_runtime.h>
#include <math.h>

namespace {

constexpr int B = 4;
constexpr int C = 512;
constexpr int NH = 32;          // heads
constexpr int CPH = 16;         // channels per head
constexpr int N = 32 * 32 * 32; // 32768 spatial
constexpr int SCH = 4;          // chunks (1024 n) per kA block
constexpr int NJB = 8;          // kA blocks per head (32 chunks / 4)
constexpr int NREC = NJB * 4;   // wave-records per head = 32
constexpr long YSIZE = (long)B * C * N;  // 67,108,864

typedef float f4v __attribute__((ext_vector_type(4)));

__device__ inline float wrs(float v) {
#pragma unroll
  for (int o = 32; o > 0; o >>= 1) v += __shfl_xor(v, o);
  return v;
}

// DPP add, compile-time control + row mask (disabled rows: old=0 added).
template <int CTRL, int RM = 0xF>
__device__ __forceinline__ float dppAdd(float v) {
  const int r = __builtin_amdgcn_update_dpp(
      0, __float_as_int(v), CTRL, RM, 0xF, true);
  return v + __int_as_float(r);
}
// Full 64-lane sum on the VALU pipe only; total valid in row 3 (lanes 48-63).
__device__ __forceinline__ float waveSumRow3(float v) {
  v = dppAdd<0xB1>(v);          // + lane^1
  v = dppAdd<0x4E>(v);          // + lane^2
  v = dppAdd<0x124>(v);         // row_ror:4
  v = dppAdd<0x128>(v);         // row_ror:8 -> 16-lane row sum
  v = dppAdd<0x142, 0xA>(v);    // row_bcast15: rows 1,3 += rows 0,2
  v = dppAdd<0x143, 0xC>(v);    // row_bcast31: rows 2,3 += lower half
  return v;
}

// ---------------------------------------------------------------------------
// kA: single pass over x. grid (8, NH, B) = 1024 blocks, 256 threads,
// __launch_bounds__(256, 2): VGPR cap 256 so the compiler has NO pressure
// reason to sink/unbatch the tile loads (R4/R13/R14 all failed because the
// allocator shrank the tile: VGPR 56/spill/64 -> serialized tiny batches).
// DOUBLE-BUFFERED register tiles: issue chunk s+1's 16-load burst, THEN
// compute on chunk s's resident tile -> per-wave compute overlaps delivery,
// breaking the "all waves deliver, then all compute" serialization.
// Per chunk: logits (no max-shift: ~unit variance, fp32 exp safe to 88),
// exp, pure-VALU DPP reductions, accumulate into o0..o3 (4 regs,
// post-reduction — valid since plain sums). Record: one 256 B interleaved
// [p][4] record/wave: float4 at p*4 = {dk[p], dq[p], cs[p],
// s-slot(p==0:sK, p==1:sQ)}. Biases & -mu*w cancel in softmax; sum_n
// attn = 1 folds mean subtraction into k4.
#define KA_LOAD(dst, s)                                                       \
  _Pragma("unroll") for (int c = 0; c < CPH; ++c)                             \
      dst[c] = *(const float4*)(xb + (long)(s) * 1024 + (long)c * N);

__global__ __launch_bounds__(256, 2) void kA(const float* __restrict__ x,
                                             const float* __restrict__ kw,
                                             const float* __restrict__ qw,
                                             float* __restrict__ prec) {
  const int b = blockIdx.z, h = blockIdx.y, j = blockIdx.x;
  const int t = threadIdx.x, lane = t & 63, wid = t >> 6;
  const int p = lane & 15;
  const float* xb = x + ((long)(b * C + h * CPH)) * N + (long)j * (SCH * 1024) + t * 4;

  float wk[CPH], wq[CPH];  // wave-uniform -> scalar
#pragma unroll
  for (int c = 0; c < CPH; ++c) {
    wk[c] = kw[h * CPH + c];
    wq[c] = qw[h * CPH + c];
  }

  float o0 = 0.f, o1 = 0.f, o2 = 0.f, o3 = 0.f;

  auto compute = [&](const float4 (&xv)[CPH]) {
    float4 lk = make_float4(0.f, 0.f, 0.f, 0.f);
    float4 lq = make_float4(0.f, 0.f, 0.f, 0.f);
#pragma unroll
    for (int c = 0; c < CPH; ++c) {
      lk.x += xv[c].x * wk[c]; lk.y += xv[c].y * wk[c];
      lk.z += xv[c].z * wk[c]; lk.w += xv[c].w * wk[c];
      lq.x += xv[c].x * wq[c]; lq.y += xv[c].y * wq[c];
      lq.z += xv[c].z * wq[c]; lq.w += xv[c].w * wq[c];
    }
    const float4 ek = make_float4(__expf(lk.x), __expf(lk.y),
                                  __expf(lk.z), __expf(lk.w));
    const float4 eq = make_float4(__expf(lq.x), __expf(lq.y),
                                  __expf(lq.z), __expf(lq.w));
    const float sK = waveSumRow3((ek.x + ek.y) + (ek.z + ek.w));
    const float sQ = waveSumRow3((eq.x + eq.y) + (eq.z + eq.w));
    o3 += (p == 0) ? sK : ((p == 1) ? sQ : 0.f);
#pragma unroll
    for (int c = 0; c < CPH; ++c) {
      float dk = (xv[c].x * ek.x + xv[c].y * ek.y) + (xv[c].z * ek.z + xv[c].w * ek.w);
      float dq = (xv[c].x * eq.x + xv[c].y * eq.y) + (xv[c].z * eq.z + xv[c].w * eq.w);
      float cs = (xv[c].x + xv[c].y) + (xv[c].z + xv[c].w);
      dk = waveSumRow3(dk); dq = waveSumRow3(dq); cs = waveSumRow3(cs);
      if (p == c) { o0 += dk; o1 += dq; o2 += cs; }
    }
  };

  float4 xvA[CPH], xvB[CPH];
  KA_LOAD(xvA, 0);            // prologue: chunk 0
  KA_LOAD(xvB, 1);            // prefetch chunk 1
  compute(xvA);               // compute 0 while 1 delivers
  KA_LOAD(xvA, 2);            // prefetch chunk 2
  compute(xvB);               // compute 1 while 2 delivers
  KA_LOAD(xvB, 3);            // prefetch chunk 3
  compute(xvA);               // compute 2 while 3 delivers
  compute(xvB);               // compute 3

  const long ridx = (((long)(b * NH + h)) * NJB + j) * 4 + wid;
  if ((lane >> 4) == 3) {  // row 3 holds the valid wave totals
    f4v r; r.x = o0; r.y = o1; r.z = o2; r.w = o3;
    *(f4v*)(prec + ridx * 64 + p * 4) = r;
  }
}

// ---------------------------------------------------------------------------
// k4: combine wave-records + finalize (R14-verified, NREC=32). grid(B),
// 512 threads (thread = channel). Reads records as float4 per channel —
// matches kA's interleaved [p][4] layout.
__global__ __launch_bounds__(512) void k4(const float* __restrict__ prec,
                                          const float* __restrict__ pw1,
                                          const float* __restrict__ pb1,
                                          const float* __restrict__ pw2,
                                          const float* __restrict__ pb2,
                                          float* __restrict__ scale,
                                          float* __restrict__ offset,
                                          float* __restrict__ dpOut) {
  const int b = blockIdx.x;
  const int c = threadIdx.x;           // 0..511
  const int h = c >> 4, i = c & 15;
  const float4* rec4 = (const float4*)prec + ((long)(b * NH + h)) * NREC * 16;

  float dk = 0.f, dq = 0.f, cs = 0.f, sacc = 0.f;
  for (int j = 0; j < NREC; ++j) {
    const float4 r = rec4[j * 16 + i];
    dk += r.x; dq += r.y; cs += r.z; sacc += r.w;  // r.w: sK at i==0, sQ at i==1
  }
  __shared__ float skS[NH], sqS[NH];
  if (i == 0) skS[h] = sacc;
  if (i == 1) sqS[h] = sacc;
  __syncthreads();
  const float sk = skS[h], sq = sqS[h];

  const float mu = cs * (1.f / N);
  const float Kv = dk / sk - mu;
  const float Qv = dq / sq - mu;

  __shared__ float muS[C], h1S[256];
  muS[c] = mu;
  __syncthreads();
  if (c < 256) {
    const int g = c >> 3;
    float a = pb1[c];
#pragma unroll
    for (int k = 0; k < 16; ++k) a += muS[g * 16 + k] * pw1[c * 16 + k];
    h1S[c] = fmaxf(a, 0.f);
  }
  __syncthreads();
  float a = pb2[c];
  const int g2 = c >> 4;
#pragma unroll
  for (int k = 0; k < 8; ++k) a += h1S[g2 * 8 + k] * pw2[c * 8 + k];
  const float P = 1.f / (1.f + __expf(-a));
  scale[b * C + c] = P;
  offset[b * C + c] = (Kv - Qv) * P;

  float pdp = wrs(Kv * Qv);
  __shared__ float pS[8];
  const int lane = c & 63, wid = c >> 6;
  if (lane == 0) pS[wid] = pdp;
  __syncthreads();
  if (c == 0) {
    float tot = 0.f;
    for (int w = 0; w < 8; ++w) tot += pS[w];
    dpOut[b] = tot * (1.f / C);
  }
}

// ---------------------------------------------------------------------------
// k5: y = x * scale[b,c] + offset[b,c] (R12-proven, unchanged).
// grid (N/4096, C, B), block 256. NT loads+stores.
__global__ __launch_bounds__(256) void k5(const float* __restrict__ x,
                                          const float* __restrict__ scale,
                                          const float* __restrict__ offset,
                                          float* __restrict__ y) {
  const int b = blockIdx.z, cc = blockIdx.y;
  const int t = threadIdx.x;
  const long base = ((long)(b * C + cc)) * N + (long)blockIdx.x * 4096;
  const float s = scale[b * C + cc], o = offset[b * C + cc];
#pragma unroll
  for (int k = 0; k < 4; ++k) {
    const long i = base + (long)(k * 256 + t) * 4;
    const f4v v = __builtin_nontemporal_load((const f4v*)(x + i));
    f4v w;
    w.x = v.x * s + o; w.y = v.y * s + o;
    w.z = v.z * s + o; w.w = v.w * s + o;
    __builtin_nontemporal_store(w, (f4v*)(y + i));
  }
}

} // namespace

extern "C" void kernel_launch(void* const* d_in, const int* in_sizes, int n_in,
                              void* d_out, int out_size, void* d_ws, size_t ws_size,
                              hipStream_t stream) {
  const float* x   = (const float*)d_in[0];
  const float* pw1 = (const float*)d_in[1];
  const float* pb1 = (const float*)d_in[2];
  const float* pw2 = (const float*)d_in[3];
  const float* pb2 = (const float*)d_in[4];
  const float* kw  = (const float*)d_in[5];
  // d_in[6]=kb, d_in[8]=qb unused: biases cancel in softmax (shift-invariant);
  // sum_n attn = 1 folds mean-subtraction into the finalize.
  const float* qw  = (const float*)d_in[7];
  float* out = (float*)d_out;
  float* ws  = (float*)d_ws;

  // scale/offset in ws (read by k5 while k5 writes out)
  float* scale  = ws;          // 2048
  float* offset = ws + 2048;   // 2048

  // wave-records: B*NH*NREC*64 = 262,144 floats (1 MB)
  constexpr long PREC = (long)B * NH * NREC * 64;
  float* prec;
  if (ws_size >= (size_t)(4096 + PREC) * sizeof(float)) {
    prec = ws + 4096;
  } else {
    prec = out;  // consumed by k4 before k5 overwrites out
  }

  hipLaunchKernelGGL(kA, dim3(NJB, NH, B), dim3(256), 0, stream,
                     x, kw, qw, prec);
  hipLaunchKernelGGL(k4, dim3(B), dim3(C), 0, stream,
                     prec, pw1, pb1, pw2, pb2, scale, offset, out + YSIZE);
  hipLaunchKernelGGL(k5, dim3(N / 4096, C, B), dim3(256), 0, stream,
                     x, scale, offset, out);
}

// Round 16
// 139.135 us; speedup vs baseline: 1.9898x; 1.0300x over previous
//
#include <hip/hip_runtime.h>
#include <math.h>

namespace {

constexpr int B = 4;
constexpr int C = 512;
constexpr int NH = 32;          // heads
constexpr int CPH = 16;         // channels per head
constexpr int N = 32 * 32 * 32; // 32768 spatial
constexpr int MST = 512;        // n per stage
constexpr int NST = 4;          // stages per block -> 2048 n per block
constexpr int NJB = 16;         // kA blocks per head (32768 / 2048)
constexpr int NREC = NJB * 4;   // wave-records per head = 64
constexpr long YSIZE = (long)B * C * N;  // 67,108,864

typedef float f4v __attribute__((ext_vector_type(4)));

__device__ inline float wrs(float v) {
#pragma unroll
  for (int o = 32; o > 0; o >>= 1) v += __shfl_xor(v, o);
  return v;
}

// DPP add, compile-time control + row mask (disabled rows: old=0 added).
template <int CTRL, int RM = 0xF>
__device__ __forceinline__ float dppAdd(float v) {
  const int r = __builtin_amdgcn_update_dpp(
      0, __float_as_int(v), CTRL, RM, 0xF, true);
  return v + __int_as_float(r);
}
// Full 64-lane sum on the VALU pipe only; total valid in row 3 (lanes 48-63).
__device__ __forceinline__ float waveSumRow3(float v) {
  v = dppAdd<0xB1>(v);          // + lane^1
  v = dppAdd<0x4E>(v);          // + lane^2
  v = dppAdd<0x124>(v);         // row_ror:4
  v = dppAdd<0x128>(v);         // row_ror:8 -> 16-lane row sum
  v = dppAdd<0x142, 0xA>(v);    // row_bcast15: rows 1,3 += rows 0,2
  v = dppAdd<0x143, 0xC>(v);    // row_bcast31: rows 2,3 += lower half
  return v;
}

// ---------------------------------------------------------------------------
// kA: single pass over x. grid (16, NH, B) = 2048 blocks, 256 threads.
// R16 experiment — DRAM STREAM SHAPE: R12's register-tile kA issues 16
// channel-strided 1 KB bursts per wave (256 concurrent streams/CU) and
// plateaus at ~4.6 TB/s; contiguous-stream kernels (k5, fills) hit ~6.9.
// Here each wave loads 4 channels as CONTIGUOUS 2 KB runs per stage
// (continuing contiguously across the block's 4 stages) into a
// double-buffered LDS tile [2][16][512] (64 KB -> 2 blocks/CU): 32 long
// streams/CU instead of 256 short ones. Compute reads LDS scalar
// (consecutive lanes -> conflict-free), accumulates per-thread dk/dq/cs
// (no register x-tile at all), then the R9-proven pure-VALU DPP tail and
// interleaved [p][4] record: float4 at p*4 = {dk[p], dq[p], cs[p],
// s-slot(p==0:sK, p==1:sQ)}. No max-shift (logits ~unit variance; fp32 exp
// safe to 88); biases & -mu*w cancel in softmax; sum_n attn = 1 folds mean
// subtraction into k4.
__global__ __launch_bounds__(256, 2) void kA(const float* __restrict__ x,
                                             const float* __restrict__ kw,
                                             const float* __restrict__ qw,
                                             float* __restrict__ prec) {
  const int b = blockIdx.z, h = blockIdx.y, j = blockIdx.x;
  const int t = threadIdx.x, lane = t & 63, wid = t >> 6;
  const int p = lane & 15;
  const float* xh = x + ((long)(b * C + h * CPH)) * N + (long)j * (NST * MST);

  __shared__ float lds[2][CPH][MST];  // 64 KB

  float wk[CPH], wq[CPH];  // wave-uniform -> scalar regs
#pragma unroll
  for (int c = 0; c < CPH; ++c) {
    wk[c] = kw[h * CPH + c];
    wq[c] = qw[h * CPH + c];
  }

  float dk[CPH], dq[CPH], cs[CPH];
#pragma unroll
  for (int c = 0; c < CPH; ++c) { dk[c] = 0.f; dq[c] = 0.f; cs[c] = 0.f; }
  float sK = 0.f, sQ = 0.f;

  // wave w stages channels w*4..w*4+3: per channel one contiguous 2 KB run
  // (2 x 1 KB wave-issues), continuing across stages.
  auto stage = [&](int s, int buf) {
    const float* src = xh + (long)s * MST;
#pragma unroll
    for (int i = 0; i < 4; ++i) {
      const int c = wid * 4 + i;
#pragma unroll
      for (int k = 0; k < 2; ++k) {
        const float4 v = *(const float4*)(src + (long)c * N + k * 256 + lane * 4);
        *(float4*)&lds[buf][c][k * 256 + lane * 4] = v;
      }
    }
  };

  auto compute = [&](int buf) {
#pragma unroll
    for (int nn = 0; nn < 2; ++nn) {
      const int n = nn * 256 + t;
      float xv[CPH];
#pragma unroll
      for (int c = 0; c < CPH; ++c) xv[c] = lds[buf][c][n];
      float lk = 0.f, lq = 0.f;
#pragma unroll
      for (int c = 0; c < CPH; ++c) { lk += xv[c] * wk[c]; lq += xv[c] * wq[c]; }
      const float ek = __expf(lk), eq = __expf(lq);
      sK += ek; sQ += eq;
#pragma unroll
      for (int c = 0; c < CPH; ++c) {
        dk[c] += xv[c] * ek;
        dq[c] += xv[c] * eq;
        cs[c] += xv[c];
      }
    }
  };

  stage(0, 0);
  __syncthreads();
#pragma unroll
  for (int s = 0; s < NST; ++s) {
    if (s + 1 < NST) stage(s + 1, (s + 1) & 1);  // loads fly under compute(s)
    compute(s & 1);
    __syncthreads();  // stage s fully consumed & stage s+1 fully written
  }

  // pure-VALU DPP reduction tail (R9-proven)
  const float tsK = waveSumRow3(sK);
  const float tsQ = waveSumRow3(sQ);
  float o0 = 0.f, o1 = 0.f, o2 = 0.f;
#pragma unroll
  for (int c = 0; c < CPH; ++c) {
    const float rk = waveSumRow3(dk[c]);
    const float rq = waveSumRow3(dq[c]);
    const float rc = waveSumRow3(cs[c]);
    if (p == c) { o0 = rk; o1 = rq; o2 = rc; }
  }
  const float o3 = (p == 0) ? tsK : ((p == 1) ? tsQ : 0.f);

  if ((lane >> 4) == 3) {  // row 3 holds the valid wave totals
    const long ridx = (((long)(b * NH + h)) * NJB + j) * 4 + wid;
    f4v r; r.x = o0; r.y = o1; r.z = o2; r.w = o3;
    *(f4v*)(prec + ridx * 64 + p * 4) = r;
  }
}

// ---------------------------------------------------------------------------
// k4: combine wave-records + finalize (R9-proven; NREC=64). grid(B),
// 512 threads (thread = channel). Reads records as float4 per channel —
// matches kA's interleaved [p][4] layout.
__global__ __launch_bounds__(512) void k4(const float* __restrict__ prec,
                                          const float* __restrict__ pw1,
                                          const float* __restrict__ pb1,
                                          const float* __restrict__ pw2,
                                          const float* __restrict__ pb2,
                                          float* __restrict__ scale,
                                          float* __restrict__ offset,
                                          float* __restrict__ dpOut) {
  const int b = blockIdx.x;
  const int c = threadIdx.x;           // 0..511
  const int h = c >> 4, i = c & 15;
  const float4* rec4 = (const float4*)prec + ((long)(b * NH + h)) * NREC * 16;

  float dk = 0.f, dq = 0.f, cs = 0.f, sacc = 0.f;
  for (int j = 0; j < NREC; ++j) {
    const float4 r = rec4[j * 16 + i];
    dk += r.x; dq += r.y; cs += r.z; sacc += r.w;  // r.w: sK at i==0, sQ at i==1
  }
  __shared__ float skS[NH], sqS[NH];
  if (i == 0) skS[h] = sacc;
  if (i == 1) sqS[h] = sacc;
  __syncthreads();
  const float sk = skS[h], sq = sqS[h];

  const float mu = cs * (1.f / N);
  const float Kv = dk / sk - mu;
  const float Qv = dq / sq - mu;

  __shared__ float muS[C], h1S[256];
  muS[c] = mu;
  __syncthreads();
  if (c < 256) {
    const int g = c >> 3;
    float a = pb1[c];
#pragma unroll
    for (int k = 0; k < 16; ++k) a += muS[g * 16 + k] * pw1[c * 16 + k];
    h1S[c] = fmaxf(a, 0.f);
  }
  __syncthreads();
  float a = pb2[c];
  const int g2 = c >> 4;
#pragma unroll
  for (int k = 0; k < 8; ++k) a += h1S[g2 * 8 + k] * pw2[c * 8 + k];
  const float P = 1.f / (1.f + __expf(-a));
  scale[b * C + c] = P;
  offset[b * C + c] = (Kv - Qv) * P;

  float pdp = wrs(Kv * Qv);
  __shared__ float pS[8];
  const int lane = c & 63, wid = c >> 6;
  if (lane == 0) pS[wid] = pdp;
  __syncthreads();
  if (c == 0) {
    float tot = 0.f;
    for (int w = 0; w < 8; ++w) tot += pS[w];
    dpOut[b] = tot * (1.f / C);
  }
}

// ---------------------------------------------------------------------------
// k5: y = x * scale[b,c] + offset[b,c] (R12-proven, unchanged).
// grid (N/4096, C, B), block 256. NT loads+stores.
__global__ __launch_bounds__(256) void k5(const float* __restrict__ x,
                                          const float* __restrict__ scale,
                                          const float* __restrict__ offset,
                                          float* __restrict__ y) {
  const int b = blockIdx.z, cc = blockIdx.y;
  const int t = threadIdx.x;
  const long base = ((long)(b * C + cc)) * N + (long)blockIdx.x * 4096;
  const float s = scale[b * C + cc], o = offset[b * C + cc];
#pragma unroll
  for (int k = 0; k < 4; ++k) {
    const long i = base + (long)(k * 256 + t) * 4;
    const f4v v = __builtin_nontemporal_load((const f4v*)(x + i));
    f4v w;
    w.x = v.x * s + o; w.y = v.y * s + o;
    w.z = v.z * s + o; w.w = v.w * s + o;
    __builtin_nontemporal_store(w, (f4v*)(y + i));
  }
}

} // namespace

extern "C" void kernel_launch(void* const* d_in, const int* in_sizes, int n_in,
                              void* d_out, int out_size, void* d_ws, size_t ws_size,
                              hipStream_t stream) {
  const float* x   = (const float*)d_in[0];
  const float* pw1 = (const float*)d_in[1];
  const float* pb1 = (const float*)d_in[2];
  const float* pw2 = (const float*)d_in[3];
  const float* pb2 = (const float*)d_in[4];
  const float* kw  = (const float*)d_in[5];
  // d_in[6]=kb, d_in[8]=qb unused: biases cancel in softmax (shift-invariant);
  // sum_n attn = 1 folds mean-subtraction into the finalize.
  const float* qw  = (const float*)d_in[7];
  float* out = (float*)d_out;
  float* ws  = (float*)d_ws;

  // scale/offset in ws (read by k5 while k5 writes out)
  float* scale  = ws;          // 2048
  float* offset = ws + 2048;   // 2048

  // wave-records: B*NH*NREC*64 = 524,288 floats (2 MB)
  constexpr long PREC = (long)B * NH * NREC * 64;
  float* prec;
  if (ws_size >= (size_t)(4096 + PREC) * sizeof(float)) {
    prec = ws + 4096;
  } else {
    prec = out;  // consumed by k4 before k5 overwrites out
  }

  hipLaunchKernelGGL(kA, dim3(NJB, NH, B), dim3(256), 0, stream,
                     x, kw, qw, prec);
  hipLaunchKernelGGL(k4, dim3(B), dim3(C), 0, stream,
                     prec, pw1, pb1, pw2, pb2, scale, offset, out + YSIZE);
  hipLaunchKernelGGL(k5, dim3(N / 4096, C, B), dim3(256), 0, stream,
                     x, scale, offset, out);
}

// Round 17
// 138.322 us; speedup vs baseline: 2.0015x; 1.0059x over previous
//
#include <hip/hip_runtime.h>
#include <math.h>

namespace {

constexpr int B = 4;
constexpr int C = 512;
constexpr int NH = 32;          // heads
constexpr int CPH = 16;         // channels per head
constexpr int N = 32 * 32 * 32; // 32768 spatial
constexpr int MST = 256;        // n per stage
constexpr int NST = 8;          // stages per block -> 2048 n per block
constexpr int NJB = 16;         // kA blocks per head (32768 / 2048)
constexpr int NREC = NJB * 4;   // wave-records per head = 64
constexpr long YSIZE = (long)B * C * N;  // 67,108,864

typedef float f4v __attribute__((ext_vector_type(4)));

__device__ inline float wrs(float v) {
#pragma unroll
  for (int o = 32; o > 0; o >>= 1) v += __shfl_xor(v, o);
  return v;
}

// DPP add, compile-time control + row mask (disabled rows: old=0 added).
template <int CTRL, int RM = 0xF>
__device__ __forceinline__ float dppAdd(float v) {
  const int r = __builtin_amdgcn_update_dpp(
      0, __float_as_int(v), CTRL, RM, 0xF, true);
  return v + __int_as_float(r);
}
// Full 64-lane sum on the VALU pipe only; total valid in row 3 (lanes 48-63).
__device__ __forceinline__ float waveSumRow3(float v) {
  v = dppAdd<0xB1>(v);          // + lane^1
  v = dppAdd<0x4E>(v);          // + lane^2
  v = dppAdd<0x124>(v);         // row_ror:4
  v = dppAdd<0x128>(v);         // row_ror:8 -> 16-lane row sum
  v = dppAdd<0x142, 0xA>(v);    // row_bcast15: rows 1,3 += rows 0,2
  v = dppAdd<0x143, 0xC>(v);    // row_bcast31: rows 2,3 += lower half
  return v;
}

// ---------------------------------------------------------------------------
// kA: single pass over x. grid (16, NH, B) = 2048 blocks, 256 threads,
// 3 blocks/CU (48 KB LDS each). R17 experiment — COUNTED-vmcnt PIPELINE:
// R16's __syncthreads staging pays a full vmcnt(0) drain at every barrier
// (compiler-inserted), stalling the 2-stage prefetch ~8 barriers/block.
// Here: 3-buffer LDS, staging via __builtin_amdgcn_global_load_lds (width
// 16; 4 issues/wave/stage; 1 KB contiguous per issue -> keeps R16's long
// per-channel DRAM streams), raw s_barrier + inline-asm s_waitcnt vmcnt(8)
// so stages s+1,s+2 stay IN FLIGHT across the barrier (vmcnt FIFO: <=8
// outstanding means stage s has landed). Drain to 4/0 only in the last two
// iterations. Barrier #2 (execution-only) protects buffer reuse.
// Compute: per-thread scalar reads lds[buf][c][t] (consecutive lanes ->
// conflict-free), logits (no max-shift: ~unit variance, fp32 exp safe to
// 88), exp, accumulate dk/dq/cs. Then the R9-proven pure-VALU DPP tail and
// interleaved [p][4] record: float4 at p*4 = {dk[p], dq[p], cs[p],
// s-slot(p==0:sK, p==1:sQ)}. Biases & -mu*w cancel in softmax; sum_n
// attn = 1 folds mean subtraction into k4.
__global__ __launch_bounds__(256, 3) void kA(const float* __restrict__ x,
                                             const float* __restrict__ kw,
                                             const float* __restrict__ qw,
                                             float* __restrict__ prec) {
  const int b = blockIdx.z, h = blockIdx.y, j = blockIdx.x;
  const int t = threadIdx.x, lane = t & 63, wid = t >> 6;
  const int p = lane & 15;
  const float* xh = x + ((long)(b * C + h * CPH)) * N + (long)j * (NST * MST);

  __shared__ float lds[3][CPH][MST];  // 48 KB

  float wk[CPH], wq[CPH];  // block-uniform -> scalar loads
#pragma unroll
  for (int c = 0; c < CPH; ++c) {
    wk[c] = kw[h * CPH + c];
    wq[c] = qw[h * CPH + c];
  }

  float dk[CPH], dq[CPH], cs[CPH];
#pragma unroll
  for (int c = 0; c < CPH; ++c) { dk[c] = 0.f; dq[c] = 0.f; cs[c] = 0.f; }
  float sK = 0.f, sQ = 0.f;

  // wave w stages channels 4w..4w+3: one global_load_lds per channel
  // (64 lanes x 16 B = 1 KB = the whole [c][0..255] stage row).
  auto stage = [&](int s) {
    const int buf = s % 3;
#pragma unroll
    for (int i = 0; i < 4; ++i) {
      const int c = wid * 4 + i;
      const float* g = xh + (long)s * MST + (long)c * N + lane * 4;
      __builtin_amdgcn_global_load_lds(
          (const __attribute__((address_space(1))) unsigned int*)g,
          (__attribute__((address_space(3))) unsigned int*)&lds[buf][c][0],
          16, 0, 0);
    }
  };

  auto compute = [&](int buf) {
    float xv[CPH];
#pragma unroll
    for (int c = 0; c < CPH; ++c) xv[c] = lds[buf][c][t];
    float lk = 0.f, lq = 0.f;
#pragma unroll
    for (int c = 0; c < CPH; ++c) { lk += xv[c] * wk[c]; lq += xv[c] * wq[c]; }
    const float ek = __expf(lk), eq = __expf(lq);
    sK += ek; sQ += eq;
#pragma unroll
    for (int c = 0; c < CPH; ++c) {
      dk[c] += xv[c] * ek;
      dq[c] += xv[c] * eq;
      cs[c] += xv[c];
    }
  };

  stage(0);
  stage(1);
#pragma unroll
  for (int s = 0; s < NST; ++s) {
    if (s + 2 < NST) stage(s + 2);
    // vmcnt is a FIFO: <=8 outstanding (4 per stage, stages s+1,s+2) means
    // stage s's 4 issues have landed. Tail: 4 then 0.
    if (s + 2 < NST)      asm volatile("s_waitcnt vmcnt(8)" ::: "memory");
    else if (s + 1 < NST) asm volatile("s_waitcnt vmcnt(4)" ::: "memory");
    else                  asm volatile("s_waitcnt vmcnt(0)" ::: "memory");
    __builtin_amdgcn_s_barrier();   // all waves' stage-s rows present
    compute(s % 3);
    asm volatile("" ::: "memory");
    __builtin_amdgcn_s_barrier();   // all waves done reading buf s%3
  }

  // pure-VALU DPP reduction tail (R9-proven)
  const float tsK = waveSumRow3(sK);
  const float tsQ = waveSumRow3(sQ);
  float o0 = 0.f, o1 = 0.f, o2 = 0.f;
#pragma unroll
  for (int c = 0; c < CPH; ++c) {
    const float rk = waveSumRow3(dk[c]);
    const float rq = waveSumRow3(dq[c]);
    const float rc = waveSumRow3(cs[c]);
    if (p == c) { o0 = rk; o1 = rq; o2 = rc; }
  }
  const float o3 = (p == 0) ? tsK : ((p == 1) ? tsQ : 0.f);

  if ((lane >> 4) == 3) {  // row 3 holds the valid wave totals
    const long ridx = (((long)(b * NH + h)) * NJB + j) * 4 + wid;
    f4v r; r.x = o0; r.y = o1; r.z = o2; r.w = o3;
    *(f4v*)(prec + ridx * 64 + p * 4) = r;
  }
}

// ---------------------------------------------------------------------------
// k4: combine wave-records + finalize (R16-proven; NREC=64). grid(B),
// 512 threads (thread = channel). Reads records as float4 per channel —
// matches kA's interleaved [p][4] layout.
__global__ __launch_bounds__(512) void k4(const float* __restrict__ prec,
                                          const float* __restrict__ pw1,
                                          const float* __restrict__ pb1,
                                          const float* __restrict__ pw2,
                                          const float* __restrict__ pb2,
                                          float* __restrict__ scale,
                                          float* __restrict__ offset,
                                          float* __restrict__ dpOut) {
  const int b = blockIdx.x;
  const int c = threadIdx.x;           // 0..511
  const int h = c >> 4, i = c & 15;
  const float4* rec4 = (const float4*)prec + ((long)(b * NH + h)) * NREC * 16;

  float dk = 0.f, dq = 0.f, cs = 0.f, sacc = 0.f;
  for (int j = 0; j < NREC; ++j) {
    const float4 r = rec4[j * 16 + i];
    dk += r.x; dq += r.y; cs += r.z; sacc += r.w;  // r.w: sK at i==0, sQ at i==1
  }
  __shared__ float skS[NH], sqS[NH];
  if (i == 0) skS[h] = sacc;
  if (i == 1) sqS[h] = sacc;
  __syncthreads();
  const float sk = skS[h], sq = sqS[h];

  const float mu = cs * (1.f / N);
  const float Kv = dk / sk - mu;
  const float Qv = dq / sq - mu;

  __shared__ float muS[C], h1S[256];
  muS[c] = mu;
  __syncthreads();
  if (c < 256) {
    const int g = c >> 3;
    float a = pb1[c];
#pragma unroll
    for (int k = 0; k < 16; ++k) a += muS[g * 16 + k] * pw1[c * 16 + k];
    h1S[c] = fmaxf(a, 0.f);
  }
  __syncthreads();
  float a = pb2[c];
  const int g2 = c >> 4;
#pragma unroll
  for (int k = 0; k < 8; ++k) a += h1S[g2 * 8 + k] * pw2[c * 8 + k];
  const float P = 1.f / (1.f + __expf(-a));
  scale[b * C + c] = P;
  offset[b * C + c] = (Kv - Qv) * P;

  float pdp = wrs(Kv * Qv);
  __shared__ float pS[8];
  const int lane = c & 63, wid = c >> 6;
  if (lane == 0) pS[wid] = pdp;
  __syncthreads();
  if (c == 0) {
    float tot = 0.f;
    for (int w = 0; w < 8; ++w) tot += pS[w];
    dpOut[b] = tot * (1.f / C);
  }
}

// ---------------------------------------------------------------------------
// k5: y = x * scale[b,c] + offset[b,c] (R12-proven, unchanged).
// grid (N/4096, C, B), block 256. NT loads+stores.
__global__ __launch_bounds__(256) void k5(const float* __restrict__ x,
                                          const float* __restrict__ scale,
                                          const float* __restrict__ offset,
                                          float* __restrict__ y) {
  const int b = blockIdx.z, cc = blockIdx.y;
  const int t = threadIdx.x;
  const long base = ((long)(b * C + cc)) * N + (long)blockIdx.x * 4096;
  const float s = scale[b * C + cc], o = offset[b * C + cc];
#pragma unroll
  for (int k = 0; k < 4; ++k) {
    const long i = base + (long)(k * 256 + t) * 4;
    const f4v v = __builtin_nontemporal_load((const f4v*)(x + i));
    f4v w;
    w.x = v.x * s + o; w.y = v.y * s + o;
    w.z = v.z * s + o; w.w = v.w * s + o;
    __builtin_nontemporal_store(w, (f4v*)(y + i));
  }
}

} // namespace

extern "C" void kernel_launch(void* const* d_in, const int* in_sizes, int n_in,
                              void* d_out, int out_size, void* d_ws, size_t ws_size,
                              hipStream_t stream) {
  const float* x   = (const float*)d_in[0];
  const float* pw1 = (const float*)d_in[1];
  const float* pb1 = (const float*)d_in[2];
  const float* pw2 = (const float*)d_in[3];
  const float* pb2 = (const float*)d_in[4];
  const float* kw  = (const float*)d_in[5];
  // d_in[6]=kb, d_in[8]=qb unused: biases cancel in softmax (shift-invariant);
  // sum_n attn = 1 folds mean-subtraction into the finalize.
  const float* qw  = (const float*)d_in[7];
  float* out = (float*)d_out;
  float* ws  = (float*)d_ws;

  // scale/offset in ws (read by k5 while k5 writes out)
  float* scale  = ws;          // 2048
  float* offset = ws + 2048;   // 2048

  // wave-records: B*NH*NREC*64 = 524,288 floats (2 MB)
  constexpr long PREC = (long)B * NH * NREC * 64;
  float* prec;
  if (ws_size >= (size_t)(4096 + PREC) * sizeof(float)) {
    prec = ws + 4096;
  } else {
    prec = out;  // consumed by k4 before k5 overwrites out
  }

  hipLaunchKernelGGL(kA, dim3(NJB, NH, B), dim3(256), 0, stream,
                     x, kw, qw, prec);
  hipLaunchKernelGGL(k4, dim3(B), dim3(C), 0, stream,
                     prec, pw1, pb1, pw2, pb2, scale, offset, out + YSIZE);
  hipLaunchKernelGGL(k5, dim3(N / 4096, C, B), dim3(256), 0, stream,
                     x, scale, offset, out);
}